// Round 4
// baseline (256.738 us; speedup 1.0000x reference)
//
#include <hip/hip_runtime.h>
#include <hip/hip_bf16.h>
#include <math.h>

#define NCLS 80
#define TOPK_N 1000
#define CAND_CAP 12288
#define T0 0.91f                // fast-path score threshold (exactness gated)
#define NB 8192                 // fallback histogram bins = key >> 17
#define HREP 8                  // fallback histogram replicas

// ---- workspace layout (bytes), M = 300000 ----
#define WS_SCORES   0           // 300000 f32 (fallback only)
#define WS_LABELS   1200000     // 300000 i32 (fallback only)
#define WS_CAND     2400000     // 12288 u64
#define WS_CANDLAB  2498304     // 12288 i32
#define WS_TKSCORE  2547456     // 1000 f32
#define WS_TKLABEL  2551456     // 1000 i32
#define WS_BOXES    2555456     // 1000 float4
#define WS_OBX      2571456     // 1000 float4 (class-offset boxes)
#define WS_AREAS    2587456     // 1000 f32
#define WS_MASK     2591456     // 1000 * 16 u64 transposed sup mask
#define WS_META     2719456     // [0]=bin B, [2]=fast counter, [3]=fb counter
#define WS_HIST     2719520     // HREP * 8192 u32
// end = 2,981,664 B

typedef unsigned long long u64;

__device__ __forceinline__ float sigmoidf_(float x) {
    return 1.0f / (1.0f + expf(-x));
}

// row max+argmax over 80 classes with 16 lanes (l = lane & 15)
__device__ __forceinline__ void rowmax16(const float4* row, int l,
                                         float& bv, int& bc) {
    float4 v4 = row[l];
    bv = v4.x; bc = l * 4;
    if (v4.y > bv) { bv = v4.y; bc = l * 4 + 1; }
    if (v4.z > bv) { bv = v4.z; bc = l * 4 + 2; }
    if (v4.w > bv) { bv = v4.w; bc = l * 4 + 3; }
    if (l < 4) {
        float4 w4 = row[16 + l];
        int cb = 64 + l * 4;
        if (w4.x > bv) { bv = w4.x; bc = cb; }
        if (w4.y > bv) { bv = w4.y; bc = cb + 1; }
        if (w4.z > bv) { bv = w4.z; bc = cb + 2; }
        if (w4.w > bv) { bv = w4.w; bc = cb + 3; }
    }
    #pragma unroll
    for (int m = 8; m >= 1; m >>= 1) {
        float ov = __shfl_xor(bv, m);
        int oc = __shfl_xor(bc, m);
        if (ov > bv || (ov == bv && oc < bc)) { bv = ov; bc = oc; }
    }
}

// K1 (fast path): stream cls, append candidates with score > T0.
__global__ void k1_scores(const float* __restrict__ obj,
                          const float* __restrict__ cls,
                          u64* __restrict__ cand,
                          int* __restrict__ candlab,
                          int* __restrict__ counter, int M) {
    int wave = (blockIdx.x * 256 + threadIdx.x) >> 6;
    int lane = threadIdx.x & 63;
    int g = lane >> 4, l = lane & 15;
    int anchor = wave * 4 + g;
    if (anchor >= M) return;
    const float4* row = (const float4*)(cls + (size_t)anchor * NCLS);
    float bv; int bc;
    rowmax16(row, l, bv, bc);
    if (l == 0) {
        float score = sqrtf(sigmoidf_(obj[anchor]) * sigmoidf_(bv));
        if (score > T0) {
            int pos = atomicAdd(counter, 1);
            if (pos < CAND_CAP) {
                cand[pos] = ((u64)__float_as_uint(score) << 32) | (unsigned)(~anchor);
                candlab[pos] = bc;
            }
        }
    }
}

// KF (fallback, gated): recompute scores+labels, build replicated histogram.
__global__ void kf_hist(const float* __restrict__ obj,
                        const float* __restrict__ cls,
                        float* __restrict__ scores,
                        int* __restrict__ labels,
                        unsigned* __restrict__ hist,
                        const int* __restrict__ meta, int M) {
    int C = meta[2];
    if (C >= TOPK_N && C <= CAND_CAP) return;     // fast path succeeded
    int gw = (blockIdx.x * 256 + threadIdx.x) >> 6;
    int TW = gridDim.x * 4;
    int lane = threadIdx.x & 63;
    int g = lane >> 4, l = lane & 15;
    int rep = blockIdx.x & (HREP - 1);
    for (int a0 = gw * 4; a0 < M; a0 += TW * 4) {
        int anchor = a0 + g;
        if (anchor >= M) continue;
        const float4* row = (const float4*)(cls + (size_t)anchor * NCLS);
        float bv; int bc;
        rowmax16(row, l, bv, bc);
        if (l == 0) {
            float score = sqrtf(sigmoidf_(obj[anchor]) * sigmoidf_(bv));
            scores[anchor] = score;
            labels[anchor] = bc;
            atomicAdd(&hist[(size_t)rep * NB + (__float_as_uint(score) >> 17)], 1u);
        }
    }
}

// K2 (fallback, gated): fold replicas + descending scan -> threshold bin.
__global__ void k2_scan(const unsigned* __restrict__ hist, int* __restrict__ meta) {
    int C = meta[2];
    if (C >= TOPK_N && C <= CAND_CAP) return;
    int t = threadIdx.x;              // 1024
    int lane = t & 63, w = t >> 6;
    int base = NB - 1 - t * 8;
    unsigned bins[8]; unsigned s = 0;
    #pragma unroll
    for (int k = 0; k < 8; ++k) {
        unsigned h = 0;
        for (int r = 0; r < HREP; ++r) h += hist[(size_t)r * NB + base - k];
        bins[k] = h; s += h;
    }
    unsigned inc = s;
    for (int d = 1; d < 64; d <<= 1) {
        unsigned pv = __shfl_up(inc, d);
        if (lane >= d) inc += pv;
    }
    __shared__ unsigned wsum[16], woff[16];
    if (lane == 63) wsum[w] = inc;
    __syncthreads();
    if (t == 0) {
        unsigned cum = 0;
        for (int i = 0; i < 16; ++i) { woff[i] = cum; cum += wsum[i]; }
    }
    __syncthreads();
    unsigned excl = woff[w] + inc - s;
    if (excl < TOPK_N && excl + s >= TOPK_N) {
        unsigned cum = excl; int b = base;
        #pragma unroll
        for (int k = 0; k < 8; ++k) {
            unsigned h = bins[k];
            if (cum + h >= TOPK_N) { meta[0] = b; break; }
            cum += h; --b;
        }
    }
}

// K3 (fallback, gated): exact compact with bin threshold.
__global__ void k3_compact(const float* __restrict__ scores,
                           const int* __restrict__ labels,
                           int* __restrict__ meta,
                           u64* __restrict__ cand,
                           int* __restrict__ candlab, int M) {
    int C = meta[2];
    if (C >= TOPK_N && C <= CAND_CAP) return;
    int B = meta[0];
    for (int i = blockIdx.x * 256 + threadIdx.x; i < M; i += gridDim.x * 256) {
        unsigned key = __float_as_uint(scores[i]);
        if ((int)(key >> 17) >= B) {
            int pos = atomicAdd(meta + 3, 1);
            if (pos < CAND_CAP) {
                cand[pos] = ((u64)key << 32) | (unsigned)(~i);
                candlab[pos] = labels[i];
            }
        }
    }
}

// K4: rank-by-counting over candidates; scatter rank < 1000.
__global__ void k4_rank(const u64* __restrict__ cand,
                        const int* __restrict__ candlab,
                        const int* __restrict__ meta,
                        const float4* __restrict__ box,
                        float* __restrict__ tkscore,
                        int* __restrict__ tklabel,
                        float4* __restrict__ boxes_k,
                        float4* __restrict__ obx,
                        float* __restrict__ areas) {
    __shared__ u64 sk[CAND_CAP];
    int Cf = meta[2];
    bool fast = (Cf >= TOPK_N && Cf <= CAND_CAP);
    int C = fast ? Cf : meta[3];
    if (C > CAND_CAP) C = CAND_CAP;
    for (int j = threadIdx.x; j < C; j += 256) sk[j] = cand[j];
    __syncthreads();
    for (int i = blockIdx.x * 256 + threadIdx.x; i < C; i += gridDim.x * 256) {
        u64 ki = sk[i];
        int rank = 0;
        for (int j = 0; j < C; ++j) rank += (sk[j] > ki);
        if (rank < TOPK_N) {
            unsigned key = (unsigned)(ki >> 32);
            int anchor = (int)(~(unsigned)ki);
            tkscore[rank] = __uint_as_float(key);
            int lab = candlab[i];
            tklabel[rank] = lab;
            float4 b = box[anchor];
            boxes_k[rank] = b;
            float off = (float)lab * 4096.0f;
            float4 ob = make_float4(b.x + off, b.y + off, b.z + off, b.w + off);
            obx[rank] = ob;
            areas[rank] = fmaxf(ob.z - ob.x, 0.0f) * fmaxf(ob.w - ob.y, 0.0f);
        }
    }
}

// K5: transposed suppression mask, 4 rows per block (4 waves).
__global__ void k5_iou(const float4* __restrict__ obx,
                       const float* __restrict__ areas,
                       u64* __restrict__ mask) {
    int i = blockIdx.x * 4 + (threadIdx.x >> 6);
    int lane = threadIdx.x & 63;
    if (i >= TOPK_N) return;
    float4 bi = obx[i];
    float ai = areas[i];
    for (int w = 0; w < 16; ++w) {
        int c = w * 64 + lane;
        bool bit = false;
        if (c < i) {
            float4 bc = obx[c];
            float xx1 = fmaxf(bi.x, bc.x), yy1 = fmaxf(bi.y, bc.y);
            float xx2 = fminf(bi.z, bc.z), yy2 = fminf(bi.w, bc.w);
            float inter = fmaxf(xx2 - xx1, 0.0f) * fmaxf(yy2 - yy1, 0.0f);
            float iou = inter / (ai + areas[c] - inter + 1e-9f);
            bit = iou > 0.5f;
        }
        u64 bal = __ballot(bit);
        if (lane == 0) mask[(size_t)i * 16 + w] = bal;
    }
}

// K6: atomic-free parallel exact greedy NMS + fused output write.
// 1024 threads = 16 waves; dec/kept word w == ballot of wave w.
__global__ void __launch_bounds__(1024)
k6_nms(const float* __restrict__ tkscore,
       const u64* __restrict__ mask,
       const int* __restrict__ tklabel,
       const float4* __restrict__ boxes_k,
       float* __restrict__ out) {
    __shared__ u64 kept_s[16], dec_s[16];
    int t = threadIdx.x, w = t >> 6, lane = t & 63;
    bool active = t < TOPK_N;
    u64 sup[16];
    float sc = 0.0f;
    if (active) {
        #pragma unroll
        for (int q = 0; q < 16; ++q) sup[q] = mask[(size_t)t * 16 + q];
        sc = tkscore[t];
    } else {
        #pragma unroll
        for (int q = 0; q < 16; ++q) sup[q] = 0ULL;
    }
    bool conf = active && (sc > 0.001f);
    bool mydec = !conf;               // inactive / low-conf: decided, not kept
    bool mykept = false;
    u64 db = __ballot(mydec), kb = __ballot(mykept);
    if (lane == 0) { dec_s[w] = db; kept_s[w] = kb; }
    __syncthreads();
    for (int round = 0; round < TOPK_N; ++round) {
        if (!mydec) {
            u64 pend = 0;
            #pragma unroll
            for (int q = 0; q < 16; ++q) pend |= sup[q] & ~dec_s[q];
            if (pend == 0ULL) {
                u64 kk = 0;
                #pragma unroll
                for (int q = 0; q < 16; ++q) kk |= sup[q] & kept_s[q];
                mydec = true; mykept = (kk == 0ULL);
            }
        }
        __syncthreads();              // reads done before republish
        db = __ballot(mydec); kb = __ballot(mykept);
        if (lane == 0) { dec_s[w] = db; kept_s[w] = kb; }
        __syncthreads();
        u64 a = ~0ULL;
        #pragma unroll
        for (int q = 0; q < 16; ++q) a &= dec_s[q];
        if (a == ~0ULL) break;
    }
    if (active) {
        float k = mykept ? 1.0f : 0.0f;
        float4 b = boxes_k[t];
        out[t * 5 + 0] = sc * k;
        out[t * 5 + 1] = b.x * k;
        out[t * 5 + 2] = b.y * k;
        out[t * 5 + 3] = b.z * k;
        out[t * 5 + 4] = b.w * k;
        out[5 * TOPK_N + t] = (float)tklabel[t];
        out[6 * TOPK_N + t] = k;
    }
}

extern "C" void kernel_launch(void* const* d_in, const int* in_sizes, int n_in,
                              void* d_out, int out_size, void* d_ws, size_t ws_size,
                              hipStream_t stream) {
    const float* obj = (const float*)d_in[0];
    const float* cls = (const float*)d_in[1];
    const float* box = (const float*)d_in[2];
    float* out = (float*)d_out;
    char* ws = (char*)d_ws;
    int M = in_sizes[0];   // 300000

    float*    scores  = (float*)(ws + WS_SCORES);
    int*      labels  = (int*)(ws + WS_LABELS);
    u64*      cand    = (u64*)(ws + WS_CAND);
    int*      candlab = (int*)(ws + WS_CANDLAB);
    float*    tkscore = (float*)(ws + WS_TKSCORE);
    int*      tklabel = (int*)(ws + WS_TKLABEL);
    float4*   boxes_k = (float4*)(ws + WS_BOXES);
    float4*   obx     = (float4*)(ws + WS_OBX);
    float*    areas   = (float*)(ws + WS_AREAS);
    u64*      mask    = (u64*)(ws + WS_MASK);
    int*      meta    = (int*)(ws + WS_META);
    unsigned* hist    = (unsigned*)(ws + WS_HIST);

    // zero meta + fallback histogram (contiguous): 64 + 256 KB
    hipMemsetAsync(ws + WS_META, 0, 64 + (size_t)HREP * NB * 4, stream);

    k1_scores<<<(M + 15) / 16, 256, 0, stream>>>(obj, cls, cand, candlab, meta + 2, M);
    kf_hist<<<512, 256, 0, stream>>>(obj, cls, scores, labels, hist, meta, M);
    k2_scan<<<1, 1024, 0, stream>>>(hist, meta);
    k3_compact<<<512, 256, 0, stream>>>(scores, labels, meta, cand, candlab, M);
    k4_rank<<<32, 256, 0, stream>>>(cand, candlab, meta, (const float4*)box,
                                    tkscore, tklabel, boxes_k, obx, areas);
    k5_iou<<<(TOPK_N + 3) / 4, 256, 0, stream>>>(obx, areas, mask);
    k6_nms<<<1, 1024, 0, stream>>>(tkscore, mask, tklabel, boxes_k, out);
}

// Round 6
// 200.760 us; speedup vs baseline: 1.2788x; 1.2788x over previous
//
#include <hip/hip_runtime.h>
#include <hip/hip_bf16.h>
#include <math.h>

#define NCLS 80
#define TOPK_N 1000
#define CAND_CAP 12288
#define T0 0.91f                // fast-path score threshold (exactness gated)
#define NB 8192                 // fallback histogram bins = key >> 17
#define HREP 8                  // fallback histogram replicas
#define RBINS 3072              // rank bins (k4 counting sort)
#define RBIN_LO 0x3F680000u     // float bits of ~0.90625
#define ANCH_INV 524287         // 2^19-1, anchor < 300000

// ---- workspace layout (bytes), M = 300000 ----
#define WS_SCORES   0           // 300000 f32 (fallback only)
#define WS_LABELS   1200000     // 300000 i32 (fallback only)
#define WS_CAND     2400000     // 12288 u64 composite keys
#define WS_TKSCORE  2498304     // 1000 f32
#define WS_TKLABEL  2502304     // 1000 i32
#define WS_BOXES    2506304     // 1000 float4
#define WS_OBX      2522304     // 1000 float4 (class-offset boxes)
#define WS_AREAS    2538304     // 1000 f32
#define WS_MASK     2542304     // 1000 * 16 u64 transposed sup mask
#define WS_META     2670304     // [0]=bin B, [2]=fast counter, [3]=fb counter
#define WS_HIST     2670368     // HREP * 8192 u32
// end = 2,932,512 B

typedef unsigned long long u64;

__device__ __forceinline__ float sigmoidf_(float x) {
    return 1.0f / (1.0f + expf(-x));
}

// composite key: [57:26]=score bits, [25:7]=(2^19-1-anchor), [6:0]=label.
// u64 descending == (score desc, anchor asc); (score,anchor) unique.
__device__ __forceinline__ u64 make_key(unsigned score32, int anchor, int lab) {
    return ((u64)score32 << 26) | ((u64)(ANCH_INV - anchor) << 7) | (unsigned)lab;
}

// BIN 0 = HIGHEST scores (descending bins), so the ascending-bin exclusive
// prefix sum = "# elements with higher score bin" = correct rank base.
// (R5 bug: this was ascending-in-score, which inverted cross-bin ranks.)
__device__ __forceinline__ int key_bin(u64 k) {
    unsigned s32 = (unsigned)(k >> 26);
    int d = (int)(s32 - RBIN_LO);
    if (d < 0) d = 0;
    int b = d >> 9;
    if (b > RBINS - 1) b = RBINS - 1;
    return (RBINS - 1) - b;
}

// row max+argmax over 80 classes with 16 lanes (l = lane & 15)
__device__ __forceinline__ void rowmax16(const float4* row, int l,
                                         float& bv, int& bc) {
    float4 v4 = row[l];
    bv = v4.x; bc = l * 4;
    if (v4.y > bv) { bv = v4.y; bc = l * 4 + 1; }
    if (v4.z > bv) { bv = v4.z; bc = l * 4 + 2; }
    if (v4.w > bv) { bv = v4.w; bc = l * 4 + 3; }
    if (l < 4) {
        float4 w4 = row[16 + l];
        int cb = 64 + l * 4;
        if (w4.x > bv) { bv = w4.x; bc = cb; }
        if (w4.y > bv) { bv = w4.y; bc = cb + 1; }
        if (w4.z > bv) { bv = w4.z; bc = cb + 2; }
        if (w4.w > bv) { bv = w4.w; bc = cb + 3; }
    }
    #pragma unroll
    for (int m = 8; m >= 1; m >>= 1) {
        float ov = __shfl_xor(bv, m);
        int oc = __shfl_xor(bc, m);
        if (ov > bv || (ov == bv && oc < bc)) { bv = ov; bc = oc; }
    }
}

// K1 (fast path): stream cls, append candidates with score > T0.
// Wave-aggregated counter atomic.
__global__ void k1_scores(const float* __restrict__ obj,
                          const float* __restrict__ cls,
                          u64* __restrict__ cand,
                          int* __restrict__ counter, int M) {
    int wave = (blockIdx.x * 256 + threadIdx.x) >> 6;
    int lane = threadIdx.x & 63;
    int g = lane >> 4, l = lane & 15;
    int anchor = wave * 4 + g;
    if (anchor >= M) return;
    const float4* row = (const float4*)(cls + (size_t)anchor * NCLS);
    float bv; int bc;
    rowmax16(row, l, bv, bc);
    float score = 0.0f;
    if (l == 0) score = sqrtf(sigmoidf_(obj[anchor]) * sigmoidf_(bv));
    bool want = (l == 0) && (score > T0);
    u64 m = __ballot(want);
    if (want) {
        int leader = __ffsll((long long)m) - 1;
        int base = 0;
        if (lane == leader) base = atomicAdd(counter, (int)__popcll(m));
        base = __shfl(base, leader);
        int pos = base + (int)__popcll(m & ((1ULL << lane) - 1ULL));
        if (pos < CAND_CAP)
            cand[pos] = make_key(__float_as_uint(score), anchor, bc);
    }
}

// KF (fallback, gated): recompute scores+labels, build replicated histogram.
__global__ void kf_hist(const float* __restrict__ obj,
                        const float* __restrict__ cls,
                        float* __restrict__ scores,
                        int* __restrict__ labels,
                        unsigned* __restrict__ hist,
                        const int* __restrict__ meta, int M) {
    int C = meta[2];
    if (C >= TOPK_N && C <= CAND_CAP) return;     // fast path succeeded
    int gw = (blockIdx.x * 256 + threadIdx.x) >> 6;
    int TW = gridDim.x * 4;
    int lane = threadIdx.x & 63;
    int g = lane >> 4, l = lane & 15;
    int rep = blockIdx.x & (HREP - 1);
    for (int a0 = gw * 4; a0 < M; a0 += TW * 4) {
        int anchor = a0 + g;
        if (anchor >= M) continue;
        const float4* row = (const float4*)(cls + (size_t)anchor * NCLS);
        float bv; int bc;
        rowmax16(row, l, bv, bc);
        if (l == 0) {
            float score = sqrtf(sigmoidf_(obj[anchor]) * sigmoidf_(bv));
            scores[anchor] = score;
            labels[anchor] = bc;
            atomicAdd(&hist[(size_t)rep * NB + (__float_as_uint(score) >> 17)], 1u);
        }
    }
}

// K2 (fallback, gated): fold replicas + descending scan -> threshold bin.
__global__ void k2_scan(const unsigned* __restrict__ hist, int* __restrict__ meta) {
    int C = meta[2];
    if (C >= TOPK_N && C <= CAND_CAP) return;
    int t = threadIdx.x;              // 1024
    int lane = t & 63, w = t >> 6;
    int base = NB - 1 - t * 8;
    unsigned bins[8]; unsigned s = 0;
    #pragma unroll
    for (int k = 0; k < 8; ++k) {
        unsigned h = 0;
        for (int r = 0; r < HREP; ++r) h += hist[(size_t)r * NB + base - k];
        bins[k] = h; s += h;
    }
    unsigned inc = s;
    for (int d = 1; d < 64; d <<= 1) {
        unsigned pv = __shfl_up(inc, d);
        if (lane >= d) inc += pv;
    }
    __shared__ unsigned wsum[16], woff[16];
    if (lane == 63) wsum[w] = inc;
    __syncthreads();
    if (t == 0) {
        unsigned cum = 0;
        for (int i = 0; i < 16; ++i) { woff[i] = cum; cum += wsum[i]; }
    }
    __syncthreads();
    unsigned excl = woff[w] + inc - s;
    if (excl < TOPK_N && excl + s >= TOPK_N) {
        unsigned cum = excl; int b = base;
        #pragma unroll
        for (int k = 0; k < 8; ++k) {
            unsigned h = bins[k];
            if (cum + h >= TOPK_N) { meta[0] = b; break; }
            cum += h; --b;
        }
    }
}

// K3 (fallback, gated): exact compact with bin threshold.
__global__ void k3_compact(const float* __restrict__ scores,
                           const int* __restrict__ labels,
                           int* __restrict__ meta,
                           u64* __restrict__ cand, int M) {
    int C = meta[2];
    if (C >= TOPK_N && C <= CAND_CAP) return;
    int B = meta[0];
    for (int i = blockIdx.x * 256 + threadIdx.x; i < M; i += gridDim.x * 256) {
        unsigned key = __float_as_uint(scores[i]);
        if ((int)(key >> 17) >= B) {
            int pos = atomicAdd(meta + 3, 1);
            if (pos < CAND_CAP)
                cand[pos] = make_key(key, i, labels[i]);
        }
    }
}

// K4: counting-sort rank. Histogram over descending score bins -> prefix sum
// -> scatter bin-sorted -> rank = bin_base + #{larger within bin}. O(C).
__global__ void __launch_bounds__(1024)
k4_rank(const u64* __restrict__ cand,
        const int* __restrict__ meta,
        const float4* __restrict__ box,
        float* __restrict__ tkscore,
        int* __restrict__ tklabel,
        float4* __restrict__ boxes_k,
        float4* __restrict__ obx,
        float* __restrict__ areas) {
    __shared__ u64 sorted[CAND_CAP];        // 98304 B
    __shared__ unsigned hist[RBINS];        // 12288 B (becomes exclusive base)
    __shared__ unsigned cnt[RBINS];         // 12288 B
    __shared__ unsigned wsum[16], woff[16];
    int t = threadIdx.x;                    // 1024
    int lane = t & 63, w = t >> 6;
    int Cf = meta[2];
    bool fast = (Cf >= TOPK_N && Cf <= CAND_CAP);
    int C = fast ? Cf : meta[3];
    if (C > CAND_CAP) C = CAND_CAP;
    for (int b = t; b < RBINS; b += 1024) { hist[b] = 0; cnt[b] = 0; }
    __syncthreads();
    // load keys (registers) + histogram
    u64 keys[12]; int nk = 0;
    for (int i = t; i < C; i += 1024) {
        u64 k = cand[i];
        keys[nk++] = k;
        atomicAdd(&hist[key_bin(k)], 1u);
    }
    __syncthreads();
    // exclusive prefix sum over RBINS (3 bins/thread)
    unsigned h0 = hist[t * 3], h1 = hist[t * 3 + 1], h2 = hist[t * 3 + 2];
    unsigned s = h0 + h1 + h2;
    unsigned inc = s;
    for (int d = 1; d < 64; d <<= 1) {
        unsigned pv = __shfl_up(inc, d);
        if (lane >= d) inc += pv;
    }
    if (lane == 63) wsum[w] = inc;
    __syncthreads();
    if (t == 0) {
        unsigned cum = 0;
        for (int i = 0; i < 16; ++i) { woff[i] = cum; cum += wsum[i]; }
    }
    __syncthreads();
    unsigned base = woff[w] + inc - s;      // exclusive base, this thread's 3 bins
    hist[t * 3] = base;
    hist[t * 3 + 1] = base + h0;
    hist[t * 3 + 2] = base + h0 + h1;
    __syncthreads();
    // scatter into bin-sorted order (bin 0 = highest scores)
    nk = 0;
    for (int i = t; i < C; i += 1024) {
        u64 k = keys[nk++];
        int b = key_bin(k);
        unsigned pos = hist[b] + atomicAdd(&cnt[b], 1u);
        sorted[pos] = k;
    }
    __syncthreads();
    // rank + output
    for (int p = t; p < C; p += 1024) {
        u64 k = sorted[p];
        int b = key_bin(k);
        unsigned b0 = hist[b], b1 = b0 + cnt[b];
        int r = (int)b0;
        for (unsigned q = b0; q < b1; ++q) r += (sorted[q] > k);
        if (r < TOPK_N) {
            unsigned s32 = (unsigned)(k >> 26);
            int anchor = ANCH_INV - (int)((k >> 7) & 0x7FFFF);
            int lab = (int)(k & 127u);
            float sc = __uint_as_float(s32);
            tkscore[r] = sc;
            tklabel[r] = lab;
            float4 bb = box[anchor];
            boxes_k[r] = bb;
            float off = (float)lab * 4096.0f;
            float4 ob = make_float4(bb.x + off, bb.y + off, bb.z + off, bb.w + off);
            obx[r] = ob;
            areas[r] = fmaxf(ob.z - ob.x, 0.0f) * fmaxf(ob.w - ob.y, 0.0f);
        }
    }
}

// K5: transposed suppression mask, 4 rows per block (4 waves).
__global__ void k5_iou(const float4* __restrict__ obx,
                       const float* __restrict__ areas,
                       u64* __restrict__ mask) {
    int i = blockIdx.x * 4 + (threadIdx.x >> 6);
    int lane = threadIdx.x & 63;
    if (i >= TOPK_N) return;
    float4 bi = obx[i];
    float ai = areas[i];
    for (int w = 0; w < 16; ++w) {
        int c = w * 64 + lane;
        bool bit = false;
        if (c < i) {
            float4 bc = obx[c];
            float xx1 = fmaxf(bi.x, bc.x), yy1 = fmaxf(bi.y, bc.y);
            float xx2 = fminf(bi.z, bc.z), yy2 = fminf(bi.w, bc.w);
            float inter = fmaxf(xx2 - xx1, 0.0f) * fmaxf(yy2 - yy1, 0.0f);
            float iou = inter / (ai + areas[c] - inter + 1e-9f);
            bit = iou > 0.5f;
        }
        u64 bal = __ballot(bit);
        if (lane == 0) mask[(size_t)i * 16 + w] = bal;
    }
}

// K6: atomic-free parallel exact greedy NMS + fused output write.
__global__ void __launch_bounds__(1024)
k6_nms(const float* __restrict__ tkscore,
       const u64* __restrict__ mask,
       const int* __restrict__ tklabel,
       const float4* __restrict__ boxes_k,
       float* __restrict__ out) {
    __shared__ u64 kept_s[16], dec_s[16];
    int t = threadIdx.x, w = t >> 6, lane = t & 63;
    bool active = t < TOPK_N;
    u64 sup[16];
    float sc = 0.0f;
    if (active) {
        #pragma unroll
        for (int q = 0; q < 16; ++q) sup[q] = mask[(size_t)t * 16 + q];
        sc = tkscore[t];
    } else {
        #pragma unroll
        for (int q = 0; q < 16; ++q) sup[q] = 0ULL;
    }
    bool conf = active && (sc > 0.001f);
    bool mydec = !conf;
    bool mykept = false;
    u64 db = __ballot(mydec), kb = __ballot(mykept);
    if (lane == 0) { dec_s[w] = db; kept_s[w] = kb; }
    __syncthreads();
    for (int round = 0; round < TOPK_N; ++round) {
        if (!mydec) {
            u64 pend = 0;
            #pragma unroll
            for (int q = 0; q < 16; ++q) pend |= sup[q] & ~dec_s[q];
            if (pend == 0ULL) {
                u64 kk = 0;
                #pragma unroll
                for (int q = 0; q < 16; ++q) kk |= sup[q] & kept_s[q];
                mydec = true; mykept = (kk == 0ULL);
            }
        }
        __syncthreads();
        db = __ballot(mydec); kb = __ballot(mykept);
        if (lane == 0) { dec_s[w] = db; kept_s[w] = kb; }
        __syncthreads();
        u64 a = ~0ULL;
        #pragma unroll
        for (int q = 0; q < 16; ++q) a &= dec_s[q];
        if (a == ~0ULL) break;
    }
    if (active) {
        float k = mykept ? 1.0f : 0.0f;
        float4 b = boxes_k[t];
        out[t * 5 + 0] = sc * k;
        out[t * 5 + 1] = b.x * k;
        out[t * 5 + 2] = b.y * k;
        out[t * 5 + 3] = b.z * k;
        out[t * 5 + 4] = b.w * k;
        out[5 * TOPK_N + t] = (float)tklabel[t];
        out[6 * TOPK_N + t] = k;
    }
}

extern "C" void kernel_launch(void* const* d_in, const int* in_sizes, int n_in,
                              void* d_out, int out_size, void* d_ws, size_t ws_size,
                              hipStream_t stream) {
    const float* obj = (const float*)d_in[0];
    const float* cls = (const float*)d_in[1];
    const float* box = (const float*)d_in[2];
    float* out = (float*)d_out;
    char* ws = (char*)d_ws;
    int M = in_sizes[0];   // 300000

    float*    scores  = (float*)(ws + WS_SCORES);
    int*      labels  = (int*)(ws + WS_LABELS);
    u64*      cand    = (u64*)(ws + WS_CAND);
    float*    tkscore = (float*)(ws + WS_TKSCORE);
    int*      tklabel = (int*)(ws + WS_TKLABEL);
    float4*   boxes_k = (float4*)(ws + WS_BOXES);
    float4*   obx     = (float4*)(ws + WS_OBX);
    float*    areas   = (float*)(ws + WS_AREAS);
    u64*      mask    = (u64*)(ws + WS_MASK);
    int*      meta    = (int*)(ws + WS_META);
    unsigned* hist    = (unsigned*)(ws + WS_HIST);

    // zero meta + fallback histogram (contiguous): 64 + 256 KB
    hipMemsetAsync(ws + WS_META, 0, 64 + (size_t)HREP * NB * 4, stream);

    k1_scores<<<(M + 15) / 16, 256, 0, stream>>>(obj, cls, cand, meta + 2, M);
    kf_hist<<<512, 256, 0, stream>>>(obj, cls, scores, labels, hist, meta, M);
    k2_scan<<<1, 1024, 0, stream>>>(hist, meta);
    k3_compact<<<512, 256, 0, stream>>>(scores, labels, meta, cand, M);
    k4_rank<<<1, 1024, 0, stream>>>(cand, meta, (const float4*)box,
                                    tkscore, tklabel, boxes_k, obx, areas);
    k5_iou<<<(TOPK_N + 3) / 4, 256, 0, stream>>>(obx, areas, mask);
    k6_nms<<<1, 1024, 0, stream>>>(tkscore, mask, tklabel, boxes_k, out);
}

// Round 7
// 190.382 us; speedup vs baseline: 1.3485x; 1.0545x over previous
//
#include <hip/hip_runtime.h>
#include <hip/hip_bf16.h>
#include <math.h>

#define NCLS 80
#define TOPK_N 1000
#define CAND_CAP 12288
#define T0 0.91f                // fast-path score threshold (exactness gated)
#define NB 8192                 // fallback histogram bins = key >> 17
#define HREP 8                  // fallback histogram replicas
#define RBINS 3072              // rank bins (k4 counting sort)
#define RBIN_LO 0x3F680000u     // float bits of ~0.90625
#define ANCH_INV 524287         // 2^19-1, anchor < 300000

// ---- workspace layout (bytes), M = 300000 ----
#define WS_SCORES   0           // 300000 f32 (fallback only)
#define WS_CAND     1200000     // 12288 u64 composite keys
#define WS_TKSCORE  1298304     // 1000 f32
#define WS_TKANCH   1302304     // 1000 i32
#define WS_TKLABEL  1306304     // 1000 i32
#define WS_BOXES    1310304     // 1000 float4
#define WS_OBX      1326304     // 1000 float4 (class-offset boxes)
#define WS_AREAS    1342304     // 1000 f32
#define WS_MASK     1346304     // 1000 * 16 u64 transposed sup mask
#define WS_META     1474304     // [0]=bin B, [2]=fast counter, [3]=fb counter
#define WS_HIST     1474368     // HREP * 8192 u32
// end = 1,736,512 B

typedef unsigned long long u64;

__device__ __forceinline__ float sigmoidf_(float x) {
    return 1.0f / (1.0f + expf(-x));
}

// composite key: [50:19]=score bits, [18:0]=(2^19-1-anchor).
// u64 descending == (score desc, anchor asc); (score,anchor) unique.
__device__ __forceinline__ u64 make_key2(unsigned s32, int anchor) {
    return ((u64)s32 << 19) | (unsigned)(ANCH_INV - anchor);
}

// BIN 0 = HIGHEST scores (descending bins): ascending-bin exclusive prefix
// sum = "# elements in higher-score bins" = correct rank base.
__device__ __forceinline__ int key_bin(u64 k) {
    unsigned s32 = (unsigned)(k >> 19);
    int d = (int)(s32 - RBIN_LO);
    if (d < 0) d = 0;
    int b = d >> 9;
    if (b > RBINS - 1) b = RBINS - 1;
    return (RBINS - 1) - b;
}

// row max+argmax over 80 classes with 16 lanes (l = lane & 15), first-max tie
__device__ __forceinline__ void rowmax16(const float4* row, int l,
                                         float& bv, int& bc) {
    float4 v4 = row[l];
    bv = v4.x; bc = l * 4;
    if (v4.y > bv) { bv = v4.y; bc = l * 4 + 1; }
    if (v4.z > bv) { bv = v4.z; bc = l * 4 + 2; }
    if (v4.w > bv) { bv = v4.w; bc = l * 4 + 3; }
    if (l < 4) {
        float4 w4 = row[16 + l];
        int cb = 64 + l * 4;
        if (w4.x > bv) { bv = w4.x; bc = cb; }
        if (w4.y > bv) { bv = w4.y; bc = cb + 1; }
        if (w4.z > bv) { bv = w4.z; bc = cb + 2; }
        if (w4.w > bv) { bv = w4.w; bc = cb + 3; }
    }
    #pragma unroll
    for (int m = 8; m >= 1; m >>= 1) {
        float ov = __shfl_xor(bv, m);
        int oc = __shfl_xor(bc, m);
        if (ov > bv || (ov == bv && oc < bc)) { bv = ov; bc = oc; }
    }
}

// K1 (fast path): max-only score scan. 16-lane group handles 4 anchors
// (4-8 loads in flight/lane). Candidates appended via LDS block aggregation.
__global__ void __launch_bounds__(256)
k1_scores(const float* __restrict__ obj,
          const float* __restrict__ cls,
          u64* __restrict__ cand,
          int* __restrict__ counter, int M) {
    __shared__ int lcount, lbase;
    __shared__ u64 lkeys[64];
    int t = threadIdx.x;
    if (t == 0) lcount = 0;
    __syncthreads();
    int l = t & 15;
    int grp = t >> 4;                         // 16 groups/block
    int base = blockIdx.x * 64 + grp * 4;     // 4 anchors/group
    if (base < M) {                           // uniform per group; M%4==0
        const float4* p = (const float4*)(cls + (size_t)base * NCLS);
        float4 a0 = p[l], a1 = p[20 + l], a2 = p[40 + l], a3 = p[60 + l];
        float m0 = fmaxf(fmaxf(a0.x, a0.y), fmaxf(a0.z, a0.w));
        float m1 = fmaxf(fmaxf(a1.x, a1.y), fmaxf(a1.z, a1.w));
        float m2 = fmaxf(fmaxf(a2.x, a2.y), fmaxf(a2.z, a2.w));
        float m3 = fmaxf(fmaxf(a3.x, a3.y), fmaxf(a3.z, a3.w));
        if (l < 4) {                          // 16-float tails of each row
            float4 b0 = p[16 + l], b1 = p[36 + l], b2 = p[56 + l], b3 = p[76 + l];
            m0 = fmaxf(m0, fmaxf(fmaxf(b0.x, b0.y), fmaxf(b0.z, b0.w)));
            m1 = fmaxf(m1, fmaxf(fmaxf(b1.x, b1.y), fmaxf(b1.z, b1.w)));
            m2 = fmaxf(m2, fmaxf(fmaxf(b2.x, b2.y), fmaxf(b2.z, b2.w)));
            m3 = fmaxf(m3, fmaxf(fmaxf(b3.x, b3.y), fmaxf(b3.z, b3.w)));
        }
        #pragma unroll
        for (int s = 8; s >= 1; s >>= 1) {
            m0 = fmaxf(m0, __shfl_xor(m0, s));
            m1 = fmaxf(m1, __shfl_xor(m1, s));
            m2 = fmaxf(m2, __shfl_xor(m2, s));
            m3 = fmaxf(m3, __shfl_xor(m3, s));
        }
        if (l < 4) {
            float mm = (l < 2) ? ((l == 0) ? m0 : m1) : ((l == 2) ? m2 : m3);
            int anchor = base + l;
            float score = sqrtf(sigmoidf_(obj[anchor]) * sigmoidf_(mm));
            if (score > T0) {
                int pos = atomicAdd(&lcount, 1);
                lkeys[pos] = make_key2(__float_as_uint(score), anchor);
            }
        }
    }
    __syncthreads();
    if (t == 0 && lcount > 0) lbase = atomicAdd(counter, lcount);
    __syncthreads();
    int n = lcount;
    if (t < n) {
        int pos = lbase + t;
        if (pos < CAND_CAP) cand[pos] = lkeys[t];
    }
}

// KF (fallback, gated): recompute scores, build replicated histogram.
__global__ void kf_hist(const float* __restrict__ obj,
                        const float* __restrict__ cls,
                        float* __restrict__ scores,
                        unsigned* __restrict__ hist,
                        const int* __restrict__ meta, int M) {
    int C = meta[2];
    if (C >= TOPK_N && C <= CAND_CAP) return;     // fast path succeeded
    int gw = (blockIdx.x * 256 + threadIdx.x) >> 6;
    int TW = gridDim.x * 4;
    int lane = threadIdx.x & 63;
    int g = lane >> 4, l = lane & 15;
    int rep = blockIdx.x & (HREP - 1);
    for (int a0 = gw * 4; a0 < M; a0 += TW * 4) {
        int anchor = a0 + g;
        if (anchor >= M) continue;
        const float4* row = (const float4*)(cls + (size_t)anchor * NCLS);
        float bv; int bc;
        rowmax16(row, l, bv, bc);
        if (l == 0) {
            float score = sqrtf(sigmoidf_(obj[anchor]) * sigmoidf_(bv));
            scores[anchor] = score;
            atomicAdd(&hist[(size_t)rep * NB + (__float_as_uint(score) >> 17)], 1u);
        }
    }
}

// K2 (fallback, gated): fold replicas + descending scan -> threshold bin.
__global__ void k2_scan(const unsigned* __restrict__ hist, int* __restrict__ meta) {
    int C = meta[2];
    if (C >= TOPK_N && C <= CAND_CAP) return;
    int t = threadIdx.x;              // 1024
    int lane = t & 63, w = t >> 6;
    int base = NB - 1 - t * 8;
    unsigned bins[8]; unsigned s = 0;
    #pragma unroll
    for (int k = 0; k < 8; ++k) {
        unsigned h = 0;
        for (int r = 0; r < HREP; ++r) h += hist[(size_t)r * NB + base - k];
        bins[k] = h; s += h;
    }
    unsigned inc = s;
    for (int d = 1; d < 64; d <<= 1) {
        unsigned pv = __shfl_up(inc, d);
        if (lane >= d) inc += pv;
    }
    __shared__ unsigned wsum[16], woff[16];
    if (lane == 63) wsum[w] = inc;
    __syncthreads();
    if (t == 0) {
        unsigned cum = 0;
        for (int i = 0; i < 16; ++i) { woff[i] = cum; cum += wsum[i]; }
    }
    __syncthreads();
    unsigned excl = woff[w] + inc - s;
    if (excl < TOPK_N && excl + s >= TOPK_N) {
        unsigned cum = excl; int b = base;
        #pragma unroll
        for (int k = 0; k < 8; ++k) {
            unsigned h = bins[k];
            if (cum + h >= TOPK_N) { meta[0] = b; break; }
            cum += h; --b;
        }
    }
}

// K3 (fallback, gated): exact compact with bin threshold.
__global__ void k3_compact(const float* __restrict__ scores,
                           int* __restrict__ meta,
                           u64* __restrict__ cand, int M) {
    int C = meta[2];
    if (C >= TOPK_N && C <= CAND_CAP) return;
    int B = meta[0];
    for (int i = blockIdx.x * 256 + threadIdx.x; i < M; i += gridDim.x * 256) {
        unsigned key = __float_as_uint(scores[i]);
        if ((int)(key >> 17) >= B) {
            int pos = atomicAdd(meta + 3, 1);
            if (pos < CAND_CAP)
                cand[pos] = make_key2(key, i);
        }
    }
}

// K4: counting-sort rank -> (tkscore, tkanchor). O(C).
__global__ void __launch_bounds__(1024)
k4_rank(const u64* __restrict__ cand,
        const int* __restrict__ meta,
        float* __restrict__ tkscore,
        int* __restrict__ tkanchor) {
    __shared__ u64 sorted[CAND_CAP];        // 98304 B
    __shared__ unsigned hist[RBINS];        // exclusive base after prefix
    __shared__ unsigned cnt[RBINS];
    __shared__ unsigned wsum[16], woff[16];
    int t = threadIdx.x;                    // 1024
    int lane = t & 63, w = t >> 6;
    int Cf = meta[2];
    bool fast = (Cf >= TOPK_N && Cf <= CAND_CAP);
    int C = fast ? Cf : meta[3];
    if (C > CAND_CAP) C = CAND_CAP;
    for (int b = t; b < RBINS; b += 1024) { hist[b] = 0; cnt[b] = 0; }
    __syncthreads();
    u64 keys[12]; int nk = 0;
    for (int i = t; i < C; i += 1024) {
        u64 k = cand[i];
        keys[nk++] = k;
        atomicAdd(&hist[key_bin(k)], 1u);
    }
    __syncthreads();
    unsigned h0 = hist[t * 3], h1 = hist[t * 3 + 1], h2 = hist[t * 3 + 2];
    unsigned s = h0 + h1 + h2;
    unsigned inc = s;
    for (int d = 1; d < 64; d <<= 1) {
        unsigned pv = __shfl_up(inc, d);
        if (lane >= d) inc += pv;
    }
    if (lane == 63) wsum[w] = inc;
    __syncthreads();
    if (t == 0) {
        unsigned cum = 0;
        for (int i = 0; i < 16; ++i) { woff[i] = cum; cum += wsum[i]; }
    }
    __syncthreads();
    unsigned base = woff[w] + inc - s;
    hist[t * 3] = base;
    hist[t * 3 + 1] = base + h0;
    hist[t * 3 + 2] = base + h0 + h1;
    __syncthreads();
    nk = 0;
    for (int i = t; i < C; i += 1024) {
        u64 k = keys[nk++];
        int b = key_bin(k);
        unsigned pos = hist[b] + atomicAdd(&cnt[b], 1u);
        sorted[pos] = k;
    }
    __syncthreads();
    for (int p = t; p < C; p += 1024) {
        u64 k = sorted[p];
        int b = key_bin(k);
        unsigned b0 = hist[b], b1 = b0 + cnt[b];
        int r = (int)b0;
        for (unsigned q = b0; q < b1; ++q) r += (sorted[q] > k);
        if (r < TOPK_N) {
            tkscore[r] = __uint_as_float((unsigned)(k >> 19));
            tkanchor[r] = ANCH_INV - (int)(k & 0x7FFFF);
        }
    }
}

// K4b: per-rank label recompute (argmax over 80) + box/obx/area gather.
// 16 lanes per rank, 16 ranks per block.
__global__ void __launch_bounds__(256)
k4b_gather(const float* __restrict__ cls,
           const float4* __restrict__ box,
           const int* __restrict__ tkanchor,
           int* __restrict__ tklabel,
           float4* __restrict__ boxes_k,
           float4* __restrict__ obx,
           float* __restrict__ areas) {
    int grp = threadIdx.x >> 4, l = threadIdx.x & 15;
    int r = blockIdx.x * 16 + grp;
    if (r >= TOPK_N) return;
    int anchor = tkanchor[r];
    const float4* row = (const float4*)(cls + (size_t)anchor * NCLS);
    float bv; int bc;
    rowmax16(row, l, bv, bc);
    if (l == 0) {
        tklabel[r] = bc;
        float4 b = box[anchor];
        boxes_k[r] = b;
        float off = (float)bc * 4096.0f;
        float4 ob = make_float4(b.x + off, b.y + off, b.z + off, b.w + off);
        obx[r] = ob;
        areas[r] = fmaxf(ob.z - ob.x, 0.0f) * fmaxf(ob.w - ob.y, 0.0f);
    }
}

// K5: transposed suppression mask: bit j of row i set iff j<i and IoU>0.5.
__global__ void k5_iou(const float4* __restrict__ obx,
                       const float* __restrict__ areas,
                       u64* __restrict__ mask) {
    int i = blockIdx.x * 4 + (threadIdx.x >> 6);
    int lane = threadIdx.x & 63;
    if (i >= TOPK_N) return;
    float4 bi = obx[i];
    float ai = areas[i];
    for (int w = 0; w < 16; ++w) {
        int c = w * 64 + lane;
        bool bit = false;
        if (c < i) {
            float4 bc = obx[c];
            float xx1 = fmaxf(bi.x, bc.x), yy1 = fmaxf(bi.y, bc.y);
            float xx2 = fminf(bi.z, bc.z), yy2 = fminf(bi.w, bc.w);
            float inter = fmaxf(xx2 - xx1, 0.0f) * fmaxf(yy2 - yy1, 0.0f);
            float iou = inter / (ai + areas[c] - inter + 1e-9f);
            bit = iou > 0.5f;
        }
        u64 bal = __ballot(bit);
        if (lane == 0) mask[(size_t)i * 16 + w] = bal;
    }
}

// K6: atomic-free parallel exact greedy NMS + fused output write.
__global__ void __launch_bounds__(1024)
k6_nms(const float* __restrict__ tkscore,
       const u64* __restrict__ mask,
       const int* __restrict__ tklabel,
       const float4* __restrict__ boxes_k,
       float* __restrict__ out) {
    __shared__ u64 kept_s[16], dec_s[16];
    int t = threadIdx.x, w = t >> 6, lane = t & 63;
    bool active = t < TOPK_N;
    u64 sup[16];
    float sc = 0.0f;
    if (active) {
        #pragma unroll
        for (int q = 0; q < 16; ++q) sup[q] = mask[(size_t)t * 16 + q];
        sc = tkscore[t];
    } else {
        #pragma unroll
        for (int q = 0; q < 16; ++q) sup[q] = 0ULL;
    }
    bool conf = active && (sc > 0.001f);
    bool mydec = !conf;
    bool mykept = false;
    u64 db = __ballot(mydec), kb = __ballot(mykept);
    if (lane == 0) { dec_s[w] = db; kept_s[w] = kb; }
    __syncthreads();
    for (int round = 0; round < TOPK_N; ++round) {
        if (!mydec) {
            u64 pend = 0;
            #pragma unroll
            for (int q = 0; q < 16; ++q) pend |= sup[q] & ~dec_s[q];
            if (pend == 0ULL) {
                u64 kk = 0;
                #pragma unroll
                for (int q = 0; q < 16; ++q) kk |= sup[q] & kept_s[q];
                mydec = true; mykept = (kk == 0ULL);
            }
        }
        __syncthreads();
        db = __ballot(mydec); kb = __ballot(mykept);
        if (lane == 0) { dec_s[w] = db; kept_s[w] = kb; }
        __syncthreads();
        u64 a = ~0ULL;
        #pragma unroll
        for (int q = 0; q < 16; ++q) a &= dec_s[q];
        if (a == ~0ULL) break;
    }
    if (active) {
        float k = mykept ? 1.0f : 0.0f;
        float4 b = boxes_k[t];
        out[t * 5 + 0] = sc * k;
        out[t * 5 + 1] = b.x * k;
        out[t * 5 + 2] = b.y * k;
        out[t * 5 + 3] = b.z * k;
        out[t * 5 + 4] = b.w * k;
        out[5 * TOPK_N + t] = (float)tklabel[t];
        out[6 * TOPK_N + t] = k;
    }
}

extern "C" void kernel_launch(void* const* d_in, const int* in_sizes, int n_in,
                              void* d_out, int out_size, void* d_ws, size_t ws_size,
                              hipStream_t stream) {
    const float* obj = (const float*)d_in[0];
    const float* cls = (const float*)d_in[1];
    const float* box = (const float*)d_in[2];
    float* out = (float*)d_out;
    char* ws = (char*)d_ws;
    int M = in_sizes[0];   // 300000

    float*    scores  = (float*)(ws + WS_SCORES);
    u64*      cand    = (u64*)(ws + WS_CAND);
    float*    tkscore = (float*)(ws + WS_TKSCORE);
    int*      tkanch  = (int*)(ws + WS_TKANCH);
    int*      tklabel = (int*)(ws + WS_TKLABEL);
    float4*   boxes_k = (float4*)(ws + WS_BOXES);
    float4*   obx     = (float4*)(ws + WS_OBX);
    float*    areas   = (float*)(ws + WS_AREAS);
    u64*      mask    = (u64*)(ws + WS_MASK);
    int*      meta    = (int*)(ws + WS_META);
    unsigned* hist    = (unsigned*)(ws + WS_HIST);

    // zero meta + fallback histogram (contiguous): 64 + 256 KB
    hipMemsetAsync(ws + WS_META, 0, 64 + (size_t)HREP * NB * 4, stream);

    k1_scores<<<(M + 63) / 64, 256, 0, stream>>>(obj, cls, cand, meta + 2, M);
    kf_hist<<<512, 256, 0, stream>>>(obj, cls, scores, hist, meta, M);
    k2_scan<<<1, 1024, 0, stream>>>(hist, meta);
    k3_compact<<<512, 256, 0, stream>>>(scores, meta, cand, M);
    k4_rank<<<1, 1024, 0, stream>>>(cand, meta, tkscore, tkanch);
    k4b_gather<<<(TOPK_N + 15) / 16, 256, 0, stream>>>(cls, (const float4*)box,
                                                       tkanch, tklabel, boxes_k, obx, areas);
    k5_iou<<<(TOPK_N + 3) / 4, 256, 0, stream>>>(obx, areas, mask);
    k6_nms<<<1, 1024, 0, stream>>>(tkscore, mask, tklabel, boxes_k, out);
}